// Round 16
// baseline (425.584 us; speedup 1.0000x reference)
//
#include <hip/hip_runtime.h>
#include <stdint.h>

#define HH 512
#define WW 512
#define HW 262144
#define CH 64
#define HID 256

typedef __attribute__((ext_vector_type(8))) short short8;
typedef __attribute__((ext_vector_type(4))) float f32x4;
typedef _Float16 f16x2 __attribute__((ext_vector_type(2)));
typedef _Float16 f16x8 __attribute__((ext_vector_type(8)));

// ws float-offset layout (wsw region):
#define WS_QKVB 0      // 128 f32  (folded q|k|v bias)
#define WS_F1B  128    // 256 f32
#define WS_F2B  384    // 64 f32
#define WS_DWP  448    // 2304 u16 f16 (dw weights [tap9][ch256])
#define WS_W1F  1600   // 16384 u16 f16 (fc1 frags [nt16][k8 8][c16][j8])
#define WS_W2F  9792   // 16384 u16 f16 (fc2 frags [nt4][k8 32][col16][j8])
#define WS_WQKV 17984  // 8192 u16 f16 (qkv B-frags [nt8][k8 8][col16][j8])
#define WS_WHP  22080  // 4096 u16 f16 (hp  A-frags [mt4][k8 8][row16][j8])

__device__ __forceinline__ float h2f(uint16_t u) {
    _Float16 h;
    __builtin_memcpy(&h, &u, 2);
    return (float)h;
}
__device__ __forceinline__ uint16_t f2h(float f) {
    _Float16 h = (_Float16)f;
    uint16_t u;
    __builtin_memcpy(&u, &h, 2);
    return u;
}
__device__ __forceinline__ f16x2 u2h2(uint32_t u) {
    f16x2 r;
    __builtin_memcpy(&r, &u, 4);
    return r;
}
// packed f32x2 -> f16x2 (v_cvt_pkrtz_f16_f32), returned as raw u32
__device__ __forceinline__ uint32_t pkrtz_u32(float a, float b) {
    auto v = __builtin_amdgcn_cvt_pkrtz(a, b);
    uint32_t u;
    __builtin_memcpy(&u, &v, 4);
    return u;
}

// tanh-form GELU
__device__ __forceinline__ float gelu_f(float v) {
    float v2 = v * v;
    float m  = v * (-1.5957691216f - 0.0713548162726f * v2);
    float e  = __expf(m);
    return v * __builtin_amdgcn_rcpf(1.f + e);
}

__global__ __launch_bounds__(256) void k0_fold(
    const float* __restrict__ q_w, const float* __restrict__ q_b,
    const float* __restrict__ k_w, const float* __restrict__ k_b,
    const float* __restrict__ v_w, const float* __restrict__ v_b,
    const float* __restrict__ bn1_g, const float* __restrict__ bn1_b,
    const float* __restrict__ bn1_m, const float* __restrict__ bn1_v,
    const float* __restrict__ fc1_w, const float* __restrict__ fc1_b,
    const float* __restrict__ bn2_g, const float* __restrict__ bn2_b,
    const float* __restrict__ bn2_m, const float* __restrict__ bn2_v,
    const float* __restrict__ fc2_w, const float* __restrict__ fc2_b,
    const float* __restrict__ hp_w,
    const float* __restrict__ dw_w, const float* __restrict__ dw_b,
    const float* __restrict__ bn3_g, const float* __restrict__ bn3_b,
    const float* __restrict__ bn3_m, const float* __restrict__ bn3_v,
    float* __restrict__ wsw)
{
    __shared__ float s1s[64], t1s[64], s2s[64], t2s[64], s3s[256], t3s[256];
    int tid = threadIdx.x;
    if (tid < 64) {
        float s = bn1_g[tid] * rsqrtf(bn1_v[tid] + 1e-5f);
        s1s[tid] = s; t1s[tid] = bn1_b[tid] - bn1_m[tid] * s;
        float s2 = bn2_g[tid] * rsqrtf(bn2_v[tid] + 1e-5f);
        s2s[tid] = s2; t2s[tid] = bn2_b[tid] - bn2_m[tid] * s2;
    }
    if (tid < 256) {
        float s = bn3_g[tid] * rsqrtf(bn3_v[tid] + 1e-5f);
        s3s[tid] = s;
        t3s[tid] = (dw_b[tid] - bn3_m[tid]) * s + bn3_b[tid];
    }
    __syncthreads();

    float* qkvb = wsw + WS_QKVB;
    float* f1b  = wsw + WS_F1B;
    float* f2b  = wsw + WS_F2B;
    uint16_t* dwph  = (uint16_t*)(wsw + WS_DWP);
    uint16_t* w1f   = (uint16_t*)(wsw + WS_W1F);
    uint16_t* w2f   = (uint16_t*)(wsw + WS_W2F);
    uint16_t* wqkvf = (uint16_t*)(wsw + WS_WQKV);
    uint16_t* whpf  = (uint16_t*)(wsw + WS_WHP);

    if (tid < 128) {
        int o = tid;
        float a;
        if (o < 32) {
            a = q_b[o];
            for (int c = 0; c < 64; c++) a += q_w[o*64+c]*t1s[c];
        } else if (o < 64) {
            a = k_b[o-32];
            for (int c = 0; c < 64; c++) a += k_w[(o-32)*64+c]*t1s[c];
        } else {
            a = v_b[o-64];
            for (int c = 0; c < 64; c++) a += v_w[(o-64)*64+c]*t1s[c];
        }
        qkvb[o] = a;
    }
    if (tid < 256) {
        float a = fc1_b[tid];
        for (int c = 0; c < 64; c++) a += fc1_w[tid*64+c]*t2s[c];
        f1b[tid] = a;
    }
    if (tid < 64) {
        float a = fc2_b[tid];
        for (int c = 0; c < 256; c++) a += fc2_w[tid*256+c]*t3s[c];
        f2b[tid] = a;
    }
    for (int i = tid; i < 8192; i += 256) {
        int nt = i >> 10, rem = i & 1023;
        int k8 = rem >> 7, col = (rem >> 3) & 15, j = rem & 7;
        int o = nt*16 + col, c = k8*8 + j;
        float w;
        if (o < 32)      w = q_w[o*64 + c];
        else if (o < 64) w = k_w[(o-32)*64 + c];
        else             w = v_w[(o-64)*64 + c];
        wqkvf[i] = f2h(w * s1s[c]);
    }
    for (int i = tid; i < 4096; i += 256) {
        int mt = i >> 10, rem = i & 1023;
        int k8 = rem >> 7, row = (rem >> 3) & 15, j = rem & 7;
        int o = mt*16 + row, c = k8*8 + j;
        whpf[i] = f2h(hp_w[o*64 + c]);
    }
    for (int i = tid; i < 16384; i += 256) {
        int nt = i >> 10, rem = i & 1023;
        int k8 = rem >> 7, col = (rem >> 3) & 15, j = rem & 7;
        int c = k8*8 + j, o = nt*16 + col;
        w1f[i] = f2h(fc1_w[o*64 + c] * s2s[c]);
    }
    // fc2 frags (f16): [nt4][k8 32][col16][j8]
    for (int i = tid; i < 16384; i += 256) {
        int nt = i >> 12, rem = i & 4095;
        int k8 = rem >> 7, col = (rem >> 3) & 15, j = rem & 7;
        int c = k8*8 + j, o = nt*16 + col;
        w2f[i] = f2h(fc2_w[o*256 + c] * s3s[c]);
    }
    // dw weights re-laid [tap][ch], f16
    for (int i = tid; i < 2304; i += 256) {
        int t = i >> 8, ch = i & 255;
        dwph[i] = f2h(dw_w[ch*9 + t]);
    }
}

// Fused: gate(x) -> qkv (f16 MFMA) -> window attention -> hp (f16 MFMA) + shortcut
// -> s1 (f16 NHWC). Coalesced halo loader, stride-170 LDS. 4 blocks/CU.
__global__ __launch_bounds__(256, 4) void k2_attn(
    const float* __restrict__ x,
    const float* __restrict__ pa_w, const float* __restrict__ pa_b,
    const float* __restrict__ hp_b,
    const float* __restrict__ wsw, uint16_t* __restrict__ s1out)
{
    // regionA: phase 1-2 = f16 halo [64 c][10 py][16], c-stride 170
    //          phase 3+ = qkv f16 [128 out][68-pad px]
    __shared__ __align__(16) uint16_t regionA[10880];
    __shared__ __align__(16) uint16_t gfrag[4096];   // gated-x f16 frags
    __shared__ __align__(16) uint16_t afrag[4096];   // att f16 B-frags
    uint16_t* xs  = regionA;
    uint16_t* qkv = regionA;

    int tid = threadIdx.x;
    int wave = tid >> 6, l = tid & 63;
    // bijective XCD swizzle (8192 % 8 == 0)
    int orig = blockIdx.x;
    int wid = (orig & 7) * 1024 + (orig >> 3);
    int b = wid >> 12;
    int r = wid & 4095;
    int wy = r >> 6, wx = r & 63;
    int y0 = wy*8 - 1;
    int x0g = wx*8 - 4;
    const float* xb = x + (size_t)b * CH * HW;
    bool interior = (wy > 0) & (wy < 63) & (wx > 0) & (wx < 63);

    // ---- phase 1: coalesced halo load (f16 via cvt_pkrtz) ----
    if (interior) {
        #pragma unroll
        for (int k = 0; k < 10; k++) {
            int i = k*256 + tid;
            int seg = i & 3;
            int rem = i >> 2;          // c*10 + py
            int c = rem / 10;
            int py = rem - c*10;
            const float* src = xb + (size_t)c*HW + (size_t)(y0+py)*512 + x0g + seg*4;
            float4 v = *reinterpret_cast<const float4*>(src);
            uint32_t lo = pkrtz_u32(v.x, v.y);
            uint32_t hi = pkrtz_u32(v.z, v.w);
            *reinterpret_cast<uint64_t*>(&xs[c*170 + py*16 + seg*4]) =
                (uint64_t)lo | ((uint64_t)hi << 32);
        }
    } else {
        #pragma unroll
        for (int k = 0; k < 10; k++) {
            int i = k*256 + tid;
            int seg = i & 3;
            int rem = i >> 2;
            int c = rem / 10;
            int py = rem - c*10;
            int yy = y0 + py;
            int gx = x0g + seg*4;
            uint64_t v64 = 0;
            if ((unsigned)yy < 512u && (unsigned)gx <= 508u) {
                float4 v = *reinterpret_cast<const float4*>(
                    xb + (size_t)c*HW + (size_t)yy*512 + gx);
                uint32_t lo = pkrtz_u32(v.x, v.y);
                uint32_t hi = pkrtz_u32(v.z, v.w);
                v64 = (uint64_t)lo | ((uint64_t)hi << 32);
            }
            *reinterpret_cast<uint64_t*>(&xs[c*170 + py*16 + seg*4]) = v64;
        }
    }
    __syncthreads();

    // ---- phase 2: gate (thread = (c, 2-row strip)) ----
    {
        int c = tid & 63, yh = tid >> 6;
        float pw[9];
        #pragma unroll
        for (int t = 0; t < 9; t++) pw[t] = pa_w[c*9 + t];
        float pb = pa_b[c];
        float va[4][12];
        #pragma unroll
        for (int tr = 0; tr < 4; tr++) {
            const uint16_t* rp = &xs[c*170 + (yh*2 + tr)*16];
            #pragma unroll
            for (int s = 0; s < 6; s++) {
                f16x2 hh = u2h2(*reinterpret_cast<const uint32_t*>(&rp[2 + s*2]));
                va[tr][s*2]   = (float)hh[0];
                va[tr][s*2+1] = (float)hh[1];
            }
        }
        #pragma unroll
        for (int dy2 = 0; dy2 < 2; dy2++) {
            int y = yh*2 + dy2;
            #pragma unroll
            for (int xx = 0; xx < 8; xx++) {
                float conv = pb;
                #pragma unroll
                for (int dy = 0; dy < 3; dy++)
                    #pragma unroll
                    for (int dx = 0; dx < 3; dx++)
                        conv += va[dy2+dy][xx+1+dx] * pw[dy*3+dx];
                float xcv = va[dy2+1][xx+2];
                float gv = xcv / (1.f + __expf(-conv));
                int n = y*8 + xx;
                gfrag[(n>>4)*1024 + (c>>3)*128 + (n&15)*8 + (c&7)] = f2h(gv);
            }
        }
    }
    __syncthreads();

    // ---- phase 3: qkv f16 MFMA -> f16 [128][68] ----
    {
        const uint16_t* wqkv = (const uint16_t*)(wsw + WS_WQKV);
        const float* qkvb = wsw + WS_QKVB;
        f32x4 acc[4][2];
        #pragma unroll
        for (int ntw = 0; ntw < 2; ntw++) {
            float bias = qkvb[(wave*2+ntw)*16 + (l & 15)];
            #pragma unroll
            for (int mt = 0; mt < 4; mt++) acc[mt][ntw] = {bias, bias, bias, bias};
        }
        #pragma unroll
        for (int kb = 0; kb < 2; kb++) {
            f16x8 a[4];
            #pragma unroll
            for (int mt = 0; mt < 4; mt++)
                a[mt] = *reinterpret_cast<const f16x8*>(&gfrag[mt*1024 + kb*512 + 8*l]);
            #pragma unroll
            for (int ntw = 0; ntw < 2; ntw++) {
                int nt = wave*2 + ntw;
                f16x8 bf = *reinterpret_cast<const f16x8*>(&wqkv[nt*1024 + kb*512 + 8*l]);
                #pragma unroll
                for (int mt = 0; mt < 4; mt++)
                    acc[mt][ntw] = __builtin_amdgcn_mfma_f32_16x16x32_f16(a[mt], bf, acc[mt][ntw], 0, 0, 0);
            }
        }
        #pragma unroll
        for (int ntw = 0; ntw < 2; ntw++) {
            int o = (wave*2+ntw)*16 + (l & 15);
            #pragma unroll
            for (int mt = 0; mt < 4; mt++) {
                int px0 = mt*16 + (l >> 4)*4;
                uint32_t lo = pkrtz_u32(acc[mt][ntw][0], acc[mt][ntw][1]);
                uint32_t hi = pkrtz_u32(acc[mt][ntw][2], acc[mt][ntw][3]);
                *reinterpret_cast<uint64_t*>(&qkv[o*68 + px0]) =
                    (uint64_t)lo | ((uint64_t)hi << 32);
            }
        }
    }
    __syncthreads();

    // ---- phase 4: attention (16-lane head groups) ----
    {
        int hd = tid >> 4, l16 = tid & 15;
        float a0[4], a1[4], a2[4], a3[4], a4[4], a5[4], a6[4], a7[4];
        #pragma unroll
        for (int j = 0; j < 4; j++) {
            int px = l16 + 16*j;
            a0[j] = h2f(qkv[(2*hd    )*68 + px]);
            a1[j] = h2f(qkv[(2*hd + 1)*68 + px]);
            a2[j] = h2f(qkv[(32 + 2*hd    )*68 + px]);
            a3[j] = h2f(qkv[(32 + 2*hd + 1)*68 + px]);
            a4[j] = h2f(qkv[(64 + 4*hd    )*68 + px]);
            a5[j] = h2f(qkv[(64 + 4*hd + 1)*68 + px]);
            a6[j] = h2f(qkv[(64 + 4*hd + 2)*68 + px]);
            a7[j] = h2f(qkv[(64 + 4*hd + 3)*68 + px]);
        }
        #pragma unroll
        for (int j = 0; j < 4; j++) {
            float m = fmaxf(a0[j], a1[j]);
            float e0 = __expf(a0[j]-m), e1 = __expf(a1[j]-m);
            float inv = 1.f/(e0+e1);
            a0[j] = e0*inv; a1[j] = e1*inv;
        }
        float m0 = fmaxf(fmaxf(a2[0],a2[1]), fmaxf(a2[2],a2[3]));
        float m1 = fmaxf(fmaxf(a3[0],a3[1]), fmaxf(a3[2],a3[3]));
        #pragma unroll
        for (int s = 1; s < 16; s <<= 1) {
            m0 = fmaxf(m0, __shfl_xor(m0, s, 64));
            m1 = fmaxf(m1, __shfl_xor(m1, s, 64));
        }
        float sum0 = 0.f, sum1 = 0.f;
        #pragma unroll
        for (int j = 0; j < 4; j++) {
            a2[j] = __expf(a2[j]-m0); a3[j] = __expf(a3[j]-m1);
            sum0 += a2[j]; sum1 += a3[j];
        }
        #pragma unroll
        for (int s = 1; s < 16; s <<= 1) {
            sum0 += __shfl_xor(sum0, s, 64);
            sum1 += __shfl_xor(sum1, s, 64);
        }
        float iv0 = 1.f/sum0, iv1 = 1.f/sum1;
        #pragma unroll
        for (int j = 0; j < 4; j++) { a2[j] *= iv0; a3[j] *= iv1; }
        float ctx0[4], ctx1[4];
        #pragma unroll
        for (int e = 0; e < 4; e++) {
            float ve0, ve1, ve2, ve3;
            if (e==0) { ve0=a4[0]; ve1=a4[1]; ve2=a4[2]; ve3=a4[3]; }
            else if (e==1) { ve0=a5[0]; ve1=a5[1]; ve2=a5[2]; ve3=a5[3]; }
            else if (e==2) { ve0=a6[0]; ve1=a6[1]; ve2=a6[2]; ve3=a6[3]; }
            else { ve0=a7[0]; ve1=a7[1]; ve2=a7[2]; ve3=a7[3]; }
            float c0 = a2[0]*ve0 + a2[1]*ve1 + a2[2]*ve2 + a2[3]*ve3;
            float c1 = a3[0]*ve0 + a3[1]*ve1 + a3[2]*ve2 + a3[3]*ve3;
            #pragma unroll
            for (int s = 1; s < 16; s <<= 1) {
                c0 += __shfl_xor(c0, s, 64);
                c1 += __shfl_xor(c1, s, 64);
            }
            ctx0[e] = c0; ctx1[e] = c1;
        }
        float p00=0.f, p01=0.f, p10=0.f, p11=0.f;
        #pragma unroll
        for (int j = 0; j < 4; j++) {
            p00 += a0[j]*a2[j]; p01 += a0[j]*a3[j];
            p10 += a1[j]*a2[j]; p11 += a1[j]*a3[j];
        }
        #pragma unroll
        for (int s = 1; s < 16; s <<= 1) {
            p00 += __shfl_xor(p00, s, 64); p01 += __shfl_xor(p01, s, 64);
            p10 += __shfl_xor(p10, s, 64); p11 += __shfl_xor(p11, s, 64);
        }
        const float CH_SCALE = 0.70710678118654752f;
        p00 *= CH_SCALE; p01 *= CH_SCALE; p10 *= CH_SCALE; p11 *= CH_SCALE;
        float dc = fmaxf(fmaxf(p00,p01), fmaxf(p10,p11)) + 0.25f*(p00+p01+p10+p11);

        #pragma unroll
        for (int j = 0; j < 4; j++) {
            uint32_t lo = pkrtz_u32((a0[j]*ctx0[0] + a1[j]*ctx1[0]) * dc,
                                    (a0[j]*ctx0[1] + a1[j]*ctx1[1]) * dc);
            uint32_t hi = pkrtz_u32((a0[j]*ctx0[2] + a1[j]*ctx1[2]) * dc,
                                    (a0[j]*ctx0[3] + a1[j]*ctx1[3]) * dc);
            *reinterpret_cast<uint64_t*>(
                &afrag[j*1024 + (hd>>1)*128 + l16*8 + (hd&1)*4]) =
                (uint64_t)lo | ((uint64_t)hi << 32);
        }
    }
    __syncthreads();

    // ---- phase 5: hp f16 MFMA + shortcut -> s1 f16 NHWC ----
    {
        const uint16_t* whp = (const uint16_t*)(wsw + WS_WHP);
        int nt = wave;
        f32x4 oacc[4];
        #pragma unroll
        for (int mt = 0; mt < 4; mt++) {
            int o0 = mt*16 + (l >> 4)*4;
            float4 hb = *reinterpret_cast<const float4*>(&hp_b[o0]);
            oacc[mt] = {hb.x, hb.y, hb.z, hb.w};
        }
        #pragma unroll
        for (int kb = 0; kb < 2; kb++) {
            f16x8 bf = *reinterpret_cast<const f16x8*>(&afrag[nt*1024 + kb*512 + 8*l]);
            #pragma unroll
            for (int mt = 0; mt < 4; mt++) {
                f16x8 a = *reinterpret_cast<const f16x8*>(&whp[mt*1024 + kb*512 + 8*l]);
                oacc[mt] = __builtin_amdgcn_mfma_f32_16x16x32_f16(a, bf, oacc[mt], 0, 0, 0);
            }
        }
        int px = nt*16 + (l & 15);
        int yy = wy*8 + (px >> 3), xx = wx*8 + (px & 7);
        size_t pbase = ((size_t)b * HW + (size_t)yy * 512 + xx) * 64;
        #pragma unroll
        for (int mt = 0; mt < 4; mt++) {
            int o0 = mt*16 + (l >> 4)*4;
            uint64_t gg = *reinterpret_cast<const uint64_t*>(
                &gfrag[(px>>4)*1024 + (o0>>3)*128 + (px&15)*8 + (o0&7)]);
            f16x2 g01 = u2h2((uint32_t)gg);
            f16x2 g23 = u2h2((uint32_t)(gg >> 32));
            uint32_t lo = pkrtz_u32(oacc[mt][0] + (float)g01[0],
                                    oacc[mt][1] + (float)g01[1]);
            uint32_t hi = pkrtz_u32(oacc[mt][2] + (float)g23[0],
                                    oacc[mt][3] + (float)g23[1]);
            *reinterpret_cast<uint64_t*>(&s1out[pbase + o0]) =
                (uint64_t)lo | ((uint64_t)hi << 32);
        }
    }
}

// Fused MLP: fc1 (f16 MFMA) + GELU + dwconv3 (pk f16) + fc2 (f16 MFMA) + residual.
// 16x8 tile, halo 18x10; 32 hidden ch/pass. Pixel fragments staged coalesced
// into LDS, copied once to registers, LDS reused as hbuf. PLAIN launch_bounds
// so the allocator can take ~100 VGPR without spilling (R14/R15 lesson).
__global__ __launch_bounds__(256) void k3_mlp(
    const uint16_t* __restrict__ s1b, const float* __restrict__ wsw,
    float* __restrict__ out)
{
    __shared__ __align__(16) uint16_t smem[12288];   // 24 KB: sfrag then hbuf
    uint16_t* sfrag = smem;                          // [12 pt][1024]
    uint16_t* hbuf  = smem;                          // f16 [180 px][36-pad ch]

    const float* f1b = wsw + WS_F1B;
    const float* f2b = wsw + WS_F2B;
    const uint16_t* dwph = (const uint16_t*)(wsw + WS_DWP);
    const uint16_t* w1f  = (const uint16_t*)(wsw + WS_W1F);
    const uint16_t* w2f  = (const uint16_t*)(wsw + WS_W2F);

    int tid = threadIdx.x;
    int wave = tid >> 6, l = tid & 63;
    int hxl = l & 15, cg = l >> 4;
    // bijective XCD swizzle over the 2048 tiles of one batch image
    int flat = blockIdx.y * 32 + blockIdx.x;
    int swz = (flat & 7) * 256 + (flat >> 3);
    int X0 = (swz & 31) * 16, Y0 = (swz >> 5) * 8;
    int b = blockIdx.z;
    bool interior = (X0 > 0) & (X0 < 496) & (Y0 > 0) & (Y0 < 504);

    // ---- phase 0: s1 halo (NHWC f16) -> sfrag, coalesced ----
    if (interior) {
        for (int i = tid; i < 1440; i += 256) {
            int px = i >> 3, g = i & 7;
            int hy = px / 18, hx = px - hy*18;
            int yy = Y0 - 1 + hy, xx = X0 - 1 + hx;
            uint4 q = *reinterpret_cast<const uint4*>(
                &s1b[((size_t)b*HW + (size_t)yy*512 + xx)*64 + g*8]);
            *reinterpret_cast<uint4*>(&sfrag[(px>>4)*1024 + g*128 + (px&15)*8]) = q;
        }
    } else {
        for (int i = tid; i < 1440; i += 256) {
            int px = i >> 3, g = i & 7;
            int hy = px / 18, hx = px - hy*18;
            int yy = Y0 - 1 + hy, xx = X0 - 1 + hx;
            uint4 q = {0u, 0u, 0u, 0u};
            if ((unsigned)yy < 512u && (unsigned)xx < 512u)
                q = *reinterpret_cast<const uint4*>(
                    &s1b[((size_t)b*HW + (size_t)yy*512 + xx)*64 + g*8]);
            *reinterpret_cast<uint4*>(&sfrag[(px>>4)*1024 + g*128 + (px&15)*8]) = q;
        }
    }
    __syncthreads();

    // ---- phase 0b: copy this thread's 6 invariant B-fragments LDS -> regs ----
    bool okA[3], imgA[3];
    int hbA[3];
    f16x8 sreg[3][2];
    #pragma unroll
    for (int it = 0; it < 3; it++) {
        int pt = wave + it*4;
        int px = pt*16 + hxl;
        okA[it] = px < 180;
        int hy = px / 18, hx = px - hy*18;
        imgA[it] = okA[it] &&
            (interior || (((unsigned)(Y0-1+hy) < 512u) && ((unsigned)(X0-1+hx) < 512u)));
        hbA[it] = px*36 + cg*4;
        #pragma unroll
        for (int kb = 0; kb < 2; kb++)
            sreg[it][kb] = *reinterpret_cast<const f16x8*>(
                &sfrag[pt*1024 + kb*512 + 8*l]);
    }

    f32x4 acc[2][4];
    #pragma unroll
    for (int nt = 0; nt < 4; nt++) {
        float bias = f2b[nt*16 + (l & 15)];
        acc[0][nt] = {bias, bias, bias, bias};
        acc[1][nt] = acc[0][nt];
    }
    __syncthreads();   // all fragment reads done; smem is now hbuf

    for (int cc = 0; cc < 8; cc++) {
        // ---- fc1 (A = weights, B = reg pixel frags) + GELU -> hbuf (f16) ----
        f16x8 wA[2][2];
        #pragma unroll
        for (int mtw = 0; mtw < 2; mtw++)
            #pragma unroll
            for (int kb = 0; kb < 2; kb++)
                wA[mtw][kb] = *reinterpret_cast<const f16x8*>(
                    &w1f[(cc*2 + mtw)*1024 + kb*512 + 8*l]);
        float4 hb0 = *reinterpret_cast<const float4*>(&f1b[cc*32      + cg*4]);
        float4 hb1 = *reinterpret_cast<const float4*>(&f1b[cc*32 + 16 + cg*4]);

        #pragma unroll
        for (int it = 0; it < 3; it++) {
            f32x4 h0 = {hb0.x, hb0.y, hb0.z, hb0.w};
            f32x4 h1 = {hb1.x, hb1.y, hb1.z, hb1.w};
            #pragma unroll
            for (int kb = 0; kb < 2; kb++) {
                h0 = __builtin_amdgcn_mfma_f32_16x16x32_f16(wA[0][kb], sreg[it][kb], h0, 0, 0, 0);
                h1 = __builtin_amdgcn_mfma_f32_16x16x32_f16(wA[1][kb], sreg[it][kb], h1, 0, 0, 0);
            }
            if (okA[it]) {
                uint64_t v0 = 0, v1 = 0;
                if (imgA[it]) {
                    uint32_t a01 = pkrtz_u32(gelu_f(h0[0]), gelu_f(h0[1]));
                    uint32_t a23 = pkrtz_u32(gelu_f(h0[2]), gelu_f(h0[3]));
                    uint32_t b01 = pkrtz_u32(gelu_f(h1[0]), gelu_f(h1[1]));
                    uint32_t b23 = pkrtz_u32(gelu_f(h1[2]), gelu_f(h1[3]));
                    v0 = (uint64_t)a01 | ((uint64_t)a23 << 32);
                    v1 = (uint64_t)b01 | ((uint64_t)b23 << 32);
                }
                *reinterpret_cast<uint64_t*>(&hbuf[hbA[it]])      = v0;
                *reinterpret_cast<uint64_t*>(&hbuf[hbA[it] + 16]) = v1;
            }
        }
        __syncthreads();

        // ---- dwconv (f16 pk math, 8 ch/thread) + fc2 f16 MFMA ----
        f16x8 bfr[4];
        #pragma unroll
        for (int nt = 0; nt < 4; nt++)
            bfr[nt] = *reinterpret_cast<const f16x8*>(&w2f[nt*4096 + cc*512 + 8*l]);

        uint4 R[4][3];
        #pragma unroll
        for (int tr = 0; tr < 4; tr++)
            #pragma unroll
            for (int dx = 0; dx < 3; dx++)
                R[tr][dx] = *reinterpret_cast<const uint4*>(
                    &hbuf[((wave*2 + tr)*18 + hxl + dx)*36 + cg*8]);

        union { f16x2 h[4]; f16x8 v; } t0, t1;
        f16x2 z = {(_Float16)0.f, (_Float16)0.f};
        #pragma unroll
        for (int g = 0; g < 4; g++) { t0.h[g] = z; t1.h[g] = z; }

        #pragma unroll
        for (int dy = 0; dy < 3; dy++) {
            #pragma unroll
            for (int dx = 0; dx < 3; dx++) {
                uint4 w = *reinterpret_cast<const uint4*>(
                    &dwph[(dy*3+dx)*256 + cc*32 + cg*8]);
                uint4 qa = R[dy][dx];
                uint4 qb = R[dy+1][dx];
                t0.h[0] += u2h2(qa.x) * u2h2(w.x);
                t0.h[1] += u2h2(qa.y) * u2h2(w.y);
                t0.h[2] += u2h2(qa.z) * u2h2(w.z);
                t0.h[3] += u2h2(qa.w) * u2h2(w.w);
                t1.h[0] += u2h2(qb.x) * u2h2(w.x);
                t1.h[1] += u2h2(qb.y) * u2h2(w.y);
                t1.h[2] += u2h2(qb.z) * u2h2(w.z);
                t1.h[3] += u2h2(qb.w) * u2h2(w.w);
            }
        }
        #pragma unroll
        for (int nt = 0; nt < 4; nt++) {
            acc[0][nt] = __builtin_amdgcn_mfma_f32_16x16x32_f16(t0.v, bfr[nt], acc[0][nt], 0, 0, 0);
            acc[1][nt] = __builtin_amdgcn_mfma_f32_16x16x32_f16(t1.v, bfr[nt], acc[1][nt], 0, 0, 0);
        }
        __syncthreads();
    }

    // ---- epilogue: + residual (f16 NHWC s1) -> out (f32 NCHW) ----
    int r0 = cg * 4;
    #pragma unroll
    for (int mi = 0; mi < 2; mi++) {
        int yrow = Y0 + wave*2 + mi;
        size_t srow = ((size_t)b*HW + (size_t)yrow*512 + X0 + r0) * 64;
        #pragma unroll
        for (int nt = 0; nt < 4; nt++) {
            int o = nt*16 + (l & 15);
            size_t oidx = ((size_t)b*CH + o)*HW + (size_t)yrow*512 + X0 + r0;
            float4 ov;
            ov.x = acc[mi][nt][0] + h2f(s1b[srow + o]);
            ov.y = acc[mi][nt][1] + h2f(s1b[srow + 64 + o]);
            ov.z = acc[mi][nt][2] + h2f(s1b[srow + 128 + o]);
            ov.w = acc[mi][nt][3] + h2f(s1b[srow + 192 + o]);
            *reinterpret_cast<float4*>(out + oidx) = ov;
        }
    }
}

extern "C" void kernel_launch(void* const* d_in, const int* in_sizes, int n_in,
                              void* d_out, int out_size, void* d_ws, size_t ws_size,
                              hipStream_t stream) {
    const float* x     = (const float*)d_in[0];
    const float* pa_w  = (const float*)d_in[1];
    const float* pa_b  = (const float*)d_in[2];
    const float* bn1_g = (const float*)d_in[3];
    const float* bn1_b = (const float*)d_in[4];
    const float* bn1_m = (const float*)d_in[5];
    const float* bn1_v = (const float*)d_in[6];
    const float* q_w   = (const float*)d_in[7];
    const float* q_b   = (const float*)d_in[8];
    const float* k_w   = (const float*)d_in[9];
    const float* k_b   = (const float*)d_in[10];
    const float* v_w   = (const float*)d_in[11];
    const float* v_b   = (const float*)d_in[12];
    const float* hp_w  = (const float*)d_in[13];
    const float* hp_b  = (const float*)d_in[14];
    const float* bn2_g = (const float*)d_in[15];
    const float* bn2_b = (const float*)d_in[16];
    const float* bn2_m = (const float*)d_in[17];
    const float* bn2_v = (const float*)d_in[18];
    const float* fc1_w = (const float*)d_in[19];
    const float* fc1_b = (const float*)d_in[20];
    const float* dw_w  = (const float*)d_in[21];
    const float* dw_b  = (const float*)d_in[22];
    const float* bn3_g = (const float*)d_in[23];
    const float* bn3_b = (const float*)d_in[24];
    const float* bn3_m = (const float*)d_in[25];
    const float* bn3_v = (const float*)d_in[26];
    const float* fc2_w = (const float*)d_in[27];
    const float* fc2_b = (const float*)d_in[28];

    uint16_t* s1b = (uint16_t*)d_ws;                                 // 67,108,864 B
    float*    wsw = (float*)((char*)d_ws + 134217728 + 268435456);   // ~100 KB

    k0_fold<<<dim3(1), dim3(256), 0, stream>>>(
        q_w, q_b, k_w, k_b, v_w, v_b,
        bn1_g, bn1_b, bn1_m, bn1_v,
        fc1_w, fc1_b, bn2_g, bn2_b, bn2_m, bn2_v,
        fc2_w, fc2_b, hp_w, dw_w, dw_b, bn3_g, bn3_b, bn3_m, bn3_v, wsw);

    k2_attn<<<dim3(8192), dim3(256), 0, stream>>>(
        x, pa_w, pa_b, hp_b, wsw, s1b);

    k3_mlp<<<dim3(32, 64, 2), dim3(256), 0, stream>>>(
        s1b, wsw, (float*)d_out);
}

// Round 17
// 290.329 us; speedup vs baseline: 1.4659x; 1.4659x over previous
//
#include <hip/hip_runtime.h>
#include <stdint.h>

#define HH 512
#define WW 512
#define HW 262144
#define CH 64
#define HID 256

typedef __attribute__((ext_vector_type(8))) short short8;
typedef __attribute__((ext_vector_type(4))) float f32x4;
typedef _Float16 f16x2 __attribute__((ext_vector_type(2)));
typedef _Float16 f16x8 __attribute__((ext_vector_type(8)));

// ws float-offset layout (wsw region):
#define WS_QKVB 0      // 128 f32  (folded q|k|v bias)
#define WS_F1B  128    // 256 f32
#define WS_F2B  384    // 64 f32
#define WS_DWP  448    // 2304 u16 f16 (dw weights [tap9][ch256])
#define WS_W1F  1600   // 16384 u16 f16 (fc1 frags [nt16][k8 8][c16][j8])
#define WS_W2F  9792   // 16384 u16 f16 (fc2 frags [nt4][k8 32][col16][j8])
#define WS_WQKV 17984  // 8192 u16 f16 (qkv B-frags [nt8][k8 8][col16][j8])
#define WS_WHP  22080  // 4096 u16 f16 (hp  A-frags [mt4][k8 8][row16][j8])

__device__ __forceinline__ float h2f(uint16_t u) {
    _Float16 h;
    __builtin_memcpy(&h, &u, 2);
    return (float)h;
}
__device__ __forceinline__ uint16_t f2h(float f) {
    _Float16 h = (_Float16)f;
    uint16_t u;
    __builtin_memcpy(&u, &h, 2);
    return u;
}
__device__ __forceinline__ f16x2 u2h2(uint32_t u) {
    f16x2 r;
    __builtin_memcpy(&r, &u, 4);
    return r;
}
// packed f32x2 -> f16x2 (v_cvt_pkrtz_f16_f32), returned as raw u32
__device__ __forceinline__ uint32_t pkrtz_u32(float a, float b) {
    auto v = __builtin_amdgcn_cvt_pkrtz(a, b);
    uint32_t u;
    __builtin_memcpy(&u, &v, 4);
    return u;
}

// tanh-form GELU
__device__ __forceinline__ float gelu_f(float v) {
    float v2 = v * v;
    float m  = v * (-1.5957691216f - 0.0713548162726f * v2);
    float e  = __expf(m);
    return v * __builtin_amdgcn_rcpf(1.f + e);
}

__global__ __launch_bounds__(256) void k0_fold(
    const float* __restrict__ q_w, const float* __restrict__ q_b,
    const float* __restrict__ k_w, const float* __restrict__ k_b,
    const float* __restrict__ v_w, const float* __restrict__ v_b,
    const float* __restrict__ bn1_g, const float* __restrict__ bn1_b,
    const float* __restrict__ bn1_m, const float* __restrict__ bn1_v,
    const float* __restrict__ fc1_w, const float* __restrict__ fc1_b,
    const float* __restrict__ bn2_g, const float* __restrict__ bn2_b,
    const float* __restrict__ bn2_m, const float* __restrict__ bn2_v,
    const float* __restrict__ fc2_w, const float* __restrict__ fc2_b,
    const float* __restrict__ hp_w,
    const float* __restrict__ dw_w, const float* __restrict__ dw_b,
    const float* __restrict__ bn3_g, const float* __restrict__ bn3_b,
    const float* __restrict__ bn3_m, const float* __restrict__ bn3_v,
    float* __restrict__ wsw)
{
    __shared__ float s1s[64], t1s[64], s2s[64], t2s[64], s3s[256], t3s[256];
    int tid = threadIdx.x;
    if (tid < 64) {
        float s = bn1_g[tid] * rsqrtf(bn1_v[tid] + 1e-5f);
        s1s[tid] = s; t1s[tid] = bn1_b[tid] - bn1_m[tid] * s;
        float s2 = bn2_g[tid] * rsqrtf(bn2_v[tid] + 1e-5f);
        s2s[tid] = s2; t2s[tid] = bn2_b[tid] - bn2_m[tid] * s2;
    }
    if (tid < 256) {
        float s = bn3_g[tid] * rsqrtf(bn3_v[tid] + 1e-5f);
        s3s[tid] = s;
        t3s[tid] = (dw_b[tid] - bn3_m[tid]) * s + bn3_b[tid];
    }
    __syncthreads();

    float* qkvb = wsw + WS_QKVB;
    float* f1b  = wsw + WS_F1B;
    float* f2b  = wsw + WS_F2B;
    uint16_t* dwph  = (uint16_t*)(wsw + WS_DWP);
    uint16_t* w1f   = (uint16_t*)(wsw + WS_W1F);
    uint16_t* w2f   = (uint16_t*)(wsw + WS_W2F);
    uint16_t* wqkvf = (uint16_t*)(wsw + WS_WQKV);
    uint16_t* whpf  = (uint16_t*)(wsw + WS_WHP);

    if (tid < 128) {
        int o = tid;
        float a;
        if (o < 32) {
            a = q_b[o];
            for (int c = 0; c < 64; c++) a += q_w[o*64+c]*t1s[c];
        } else if (o < 64) {
            a = k_b[o-32];
            for (int c = 0; c < 64; c++) a += k_w[(o-32)*64+c]*t1s[c];
        } else {
            a = v_b[o-64];
            for (int c = 0; c < 64; c++) a += v_w[(o-64)*64+c]*t1s[c];
        }
        qkvb[o] = a;
    }
    if (tid < 256) {
        float a = fc1_b[tid];
        for (int c = 0; c < 64; c++) a += fc1_w[tid*64+c]*t2s[c];
        f1b[tid] = a;
    }
    if (tid < 64) {
        float a = fc2_b[tid];
        for (int c = 0; c < 256; c++) a += fc2_w[tid*256+c]*t3s[c];
        f2b[tid] = a;
    }
    for (int i = tid; i < 8192; i += 256) {
        int nt = i >> 10, rem = i & 1023;
        int k8 = rem >> 7, col = (rem >> 3) & 15, j = rem & 7;
        int o = nt*16 + col, c = k8*8 + j;
        float w;
        if (o < 32)      w = q_w[o*64 + c];
        else if (o < 64) w = k_w[(o-32)*64 + c];
        else             w = v_w[(o-64)*64 + c];
        wqkvf[i] = f2h(w * s1s[c]);
    }
    for (int i = tid; i < 4096; i += 256) {
        int mt = i >> 10, rem = i & 1023;
        int k8 = rem >> 7, row = (rem >> 3) & 15, j = rem & 7;
        int o = mt*16 + row, c = k8*8 + j;
        whpf[i] = f2h(hp_w[o*64 + c]);
    }
    for (int i = tid; i < 16384; i += 256) {
        int nt = i >> 10, rem = i & 1023;
        int k8 = rem >> 7, col = (rem >> 3) & 15, j = rem & 7;
        int c = k8*8 + j, o = nt*16 + col;
        w1f[i] = f2h(fc1_w[o*64 + c] * s2s[c]);
    }
    // fc2 frags (f16): [nt4][k8 32][col16][j8]
    for (int i = tid; i < 16384; i += 256) {
        int nt = i >> 12, rem = i & 4095;
        int k8 = rem >> 7, col = (rem >> 3) & 15, j = rem & 7;
        int c = k8*8 + j, o = nt*16 + col;
        w2f[i] = f2h(fc2_w[o*256 + c] * s3s[c]);
    }
    // dw weights re-laid [tap][ch], f16
    for (int i = tid; i < 2304; i += 256) {
        int t = i >> 8, ch = i & 255;
        dwph[i] = f2h(dw_w[ch*9 + t]);
    }
}

// Fused: gate(x) -> qkv (f16 MFMA) -> window attention -> hp (f16 MFMA) + shortcut
// -> s1 (f16 NHWC). Coalesced halo loader, stride-170 LDS. 4 blocks/CU.
__global__ __launch_bounds__(256, 4) void k2_attn(
    const float* __restrict__ x,
    const float* __restrict__ pa_w, const float* __restrict__ pa_b,
    const float* __restrict__ hp_b,
    const float* __restrict__ wsw, uint16_t* __restrict__ s1out)
{
    // regionA: phase 1-2 = f16 halo [64 c][10 py][16], c-stride 170
    //          phase 3+ = qkv f16 [128 out][68-pad px]
    __shared__ __align__(16) uint16_t regionA[10880];
    __shared__ __align__(16) uint16_t gfrag[4096];   // gated-x f16 frags
    __shared__ __align__(16) uint16_t afrag[4096];   // att f16 B-frags
    uint16_t* xs  = regionA;
    uint16_t* qkv = regionA;

    int tid = threadIdx.x;
    int wave = tid >> 6, l = tid & 63;
    // bijective XCD swizzle (8192 % 8 == 0)
    int orig = blockIdx.x;
    int wid = (orig & 7) * 1024 + (orig >> 3);
    int b = wid >> 12;
    int r = wid & 4095;
    int wy = r >> 6, wx = r & 63;
    int y0 = wy*8 - 1;
    int x0g = wx*8 - 4;
    const float* xb = x + (size_t)b * CH * HW;
    bool interior = (wy > 0) & (wy < 63) & (wx > 0) & (wx < 63);

    // ---- phase 1: coalesced halo load (f16 via cvt_pkrtz) ----
    if (interior) {
        #pragma unroll
        for (int k = 0; k < 10; k++) {
            int i = k*256 + tid;
            int seg = i & 3;
            int rem = i >> 2;          // c*10 + py
            int c = rem / 10;
            int py = rem - c*10;
            const float* src = xb + (size_t)c*HW + (size_t)(y0+py)*512 + x0g + seg*4;
            float4 v = *reinterpret_cast<const float4*>(src);
            uint32_t lo = pkrtz_u32(v.x, v.y);
            uint32_t hi = pkrtz_u32(v.z, v.w);
            *reinterpret_cast<uint64_t*>(&xs[c*170 + py*16 + seg*4]) =
                (uint64_t)lo | ((uint64_t)hi << 32);
        }
    } else {
        #pragma unroll
        for (int k = 0; k < 10; k++) {
            int i = k*256 + tid;
            int seg = i & 3;
            int rem = i >> 2;
            int c = rem / 10;
            int py = rem - c*10;
            int yy = y0 + py;
            int gx = x0g + seg*4;
            uint64_t v64 = 0;
            if ((unsigned)yy < 512u && (unsigned)gx <= 508u) {
                float4 v = *reinterpret_cast<const float4*>(
                    xb + (size_t)c*HW + (size_t)yy*512 + gx);
                uint32_t lo = pkrtz_u32(v.x, v.y);
                uint32_t hi = pkrtz_u32(v.z, v.w);
                v64 = (uint64_t)lo | ((uint64_t)hi << 32);
            }
            *reinterpret_cast<uint64_t*>(&xs[c*170 + py*16 + seg*4]) = v64;
        }
    }
    __syncthreads();

    // ---- phase 2: gate (thread = (c, 2-row strip)) ----
    {
        int c = tid & 63, yh = tid >> 6;
        float pw[9];
        #pragma unroll
        for (int t = 0; t < 9; t++) pw[t] = pa_w[c*9 + t];
        float pb = pa_b[c];
        float va[4][12];
        #pragma unroll
        for (int tr = 0; tr < 4; tr++) {
            const uint16_t* rp = &xs[c*170 + (yh*2 + tr)*16];
            #pragma unroll
            for (int s = 0; s < 6; s++) {
                f16x2 hh = u2h2(*reinterpret_cast<const uint32_t*>(&rp[2 + s*2]));
                va[tr][s*2]   = (float)hh[0];
                va[tr][s*2+1] = (float)hh[1];
            }
        }
        #pragma unroll
        for (int dy2 = 0; dy2 < 2; dy2++) {
            int y = yh*2 + dy2;
            #pragma unroll
            for (int xx = 0; xx < 8; xx++) {
                float conv = pb;
                #pragma unroll
                for (int dy = 0; dy < 3; dy++)
                    #pragma unroll
                    for (int dx = 0; dx < 3; dx++)
                        conv += va[dy2+dy][xx+1+dx] * pw[dy*3+dx];
                float xcv = va[dy2+1][xx+2];
                float gv = xcv / (1.f + __expf(-conv));
                int n = y*8 + xx;
                gfrag[(n>>4)*1024 + (c>>3)*128 + (n&15)*8 + (c&7)] = f2h(gv);
            }
        }
    }
    __syncthreads();

    // ---- phase 3: qkv f16 MFMA -> f16 [128][68] ----
    {
        const uint16_t* wqkv = (const uint16_t*)(wsw + WS_WQKV);
        const float* qkvb = wsw + WS_QKVB;
        f32x4 acc[4][2];
        #pragma unroll
        for (int ntw = 0; ntw < 2; ntw++) {
            float bias = qkvb[(wave*2+ntw)*16 + (l & 15)];
            #pragma unroll
            for (int mt = 0; mt < 4; mt++) acc[mt][ntw] = {bias, bias, bias, bias};
        }
        #pragma unroll
        for (int kb = 0; kb < 2; kb++) {
            f16x8 a[4];
            #pragma unroll
            for (int mt = 0; mt < 4; mt++)
                a[mt] = *reinterpret_cast<const f16x8*>(&gfrag[mt*1024 + kb*512 + 8*l]);
            #pragma unroll
            for (int ntw = 0; ntw < 2; ntw++) {
                int nt = wave*2 + ntw;
                f16x8 bf = *reinterpret_cast<const f16x8*>(&wqkv[nt*1024 + kb*512 + 8*l]);
                #pragma unroll
                for (int mt = 0; mt < 4; mt++)
                    acc[mt][ntw] = __builtin_amdgcn_mfma_f32_16x16x32_f16(a[mt], bf, acc[mt][ntw], 0, 0, 0);
            }
        }
        #pragma unroll
        for (int ntw = 0; ntw < 2; ntw++) {
            int o = (wave*2+ntw)*16 + (l & 15);
            #pragma unroll
            for (int mt = 0; mt < 4; mt++) {
                int px0 = mt*16 + (l >> 4)*4;
                uint32_t lo = pkrtz_u32(acc[mt][ntw][0], acc[mt][ntw][1]);
                uint32_t hi = pkrtz_u32(acc[mt][ntw][2], acc[mt][ntw][3]);
                *reinterpret_cast<uint64_t*>(&qkv[o*68 + px0]) =
                    (uint64_t)lo | ((uint64_t)hi << 32);
            }
        }
    }
    __syncthreads();

    // ---- phase 4: attention (16-lane head groups) ----
    {
        int hd = tid >> 4, l16 = tid & 15;
        float a0[4], a1[4], a2[4], a3[4], a4[4], a5[4], a6[4], a7[4];
        #pragma unroll
        for (int j = 0; j < 4; j++) {
            int px = l16 + 16*j;
            a0[j] = h2f(qkv[(2*hd    )*68 + px]);
            a1[j] = h2f(qkv[(2*hd + 1)*68 + px]);
            a2[j] = h2f(qkv[(32 + 2*hd    )*68 + px]);
            a3[j] = h2f(qkv[(32 + 2*hd + 1)*68 + px]);
            a4[j] = h2f(qkv[(64 + 4*hd    )*68 + px]);
            a5[j] = h2f(qkv[(64 + 4*hd + 1)*68 + px]);
            a6[j] = h2f(qkv[(64 + 4*hd + 2)*68 + px]);
            a7[j] = h2f(qkv[(64 + 4*hd + 3)*68 + px]);
        }
        #pragma unroll
        for (int j = 0; j < 4; j++) {
            float m = fmaxf(a0[j], a1[j]);
            float e0 = __expf(a0[j]-m), e1 = __expf(a1[j]-m);
            float inv = 1.f/(e0+e1);
            a0[j] = e0*inv; a1[j] = e1*inv;
        }
        float m0 = fmaxf(fmaxf(a2[0],a2[1]), fmaxf(a2[2],a2[3]));
        float m1 = fmaxf(fmaxf(a3[0],a3[1]), fmaxf(a3[2],a3[3]));
        #pragma unroll
        for (int s = 1; s < 16; s <<= 1) {
            m0 = fmaxf(m0, __shfl_xor(m0, s, 64));
            m1 = fmaxf(m1, __shfl_xor(m1, s, 64));
        }
        float sum0 = 0.f, sum1 = 0.f;
        #pragma unroll
        for (int j = 0; j < 4; j++) {
            a2[j] = __expf(a2[j]-m0); a3[j] = __expf(a3[j]-m1);
            sum0 += a2[j]; sum1 += a3[j];
        }
        #pragma unroll
        for (int s = 1; s < 16; s <<= 1) {
            sum0 += __shfl_xor(sum0, s, 64);
            sum1 += __shfl_xor(sum1, s, 64);
        }
        float iv0 = 1.f/sum0, iv1 = 1.f/sum1;
        #pragma unroll
        for (int j = 0; j < 4; j++) { a2[j] *= iv0; a3[j] *= iv1; }
        float ctx0[4], ctx1[4];
        #pragma unroll
        for (int e = 0; e < 4; e++) {
            float ve0, ve1, ve2, ve3;
            if (e==0) { ve0=a4[0]; ve1=a4[1]; ve2=a4[2]; ve3=a4[3]; }
            else if (e==1) { ve0=a5[0]; ve1=a5[1]; ve2=a5[2]; ve3=a5[3]; }
            else if (e==2) { ve0=a6[0]; ve1=a6[1]; ve2=a6[2]; ve3=a6[3]; }
            else { ve0=a7[0]; ve1=a7[1]; ve2=a7[2]; ve3=a7[3]; }
            float c0 = a2[0]*ve0 + a2[1]*ve1 + a2[2]*ve2 + a2[3]*ve3;
            float c1 = a3[0]*ve0 + a3[1]*ve1 + a3[2]*ve2 + a3[3]*ve3;
            #pragma unroll
            for (int s = 1; s < 16; s <<= 1) {
                c0 += __shfl_xor(c0, s, 64);
                c1 += __shfl_xor(c1, s, 64);
            }
            ctx0[e] = c0; ctx1[e] = c1;
        }
        float p00=0.f, p01=0.f, p10=0.f, p11=0.f;
        #pragma unroll
        for (int j = 0; j < 4; j++) {
            p00 += a0[j]*a2[j]; p01 += a0[j]*a3[j];
            p10 += a1[j]*a2[j]; p11 += a1[j]*a3[j];
        }
        #pragma unroll
        for (int s = 1; s < 16; s <<= 1) {
            p00 += __shfl_xor(p00, s, 64); p01 += __shfl_xor(p01, s, 64);
            p10 += __shfl_xor(p10, s, 64); p11 += __shfl_xor(p11, s, 64);
        }
        const float CH_SCALE = 0.70710678118654752f;
        p00 *= CH_SCALE; p01 *= CH_SCALE; p10 *= CH_SCALE; p11 *= CH_SCALE;
        float dc = fmaxf(fmaxf(p00,p01), fmaxf(p10,p11)) + 0.25f*(p00+p01+p10+p11);

        #pragma unroll
        for (int j = 0; j < 4; j++) {
            uint32_t lo = pkrtz_u32((a0[j]*ctx0[0] + a1[j]*ctx1[0]) * dc,
                                    (a0[j]*ctx0[1] + a1[j]*ctx1[1]) * dc);
            uint32_t hi = pkrtz_u32((a0[j]*ctx0[2] + a1[j]*ctx1[2]) * dc,
                                    (a0[j]*ctx0[3] + a1[j]*ctx1[3]) * dc);
            *reinterpret_cast<uint64_t*>(
                &afrag[j*1024 + (hd>>1)*128 + l16*8 + (hd&1)*4]) =
                (uint64_t)lo | ((uint64_t)hi << 32);
        }
    }
    __syncthreads();

    // ---- phase 5: hp f16 MFMA + shortcut -> s1 f16 NHWC ----
    {
        const uint16_t* whp = (const uint16_t*)(wsw + WS_WHP);
        int nt = wave;
        f32x4 oacc[4];
        #pragma unroll
        for (int mt = 0; mt < 4; mt++) {
            int o0 = mt*16 + (l >> 4)*4;
            float4 hb = *reinterpret_cast<const float4*>(&hp_b[o0]);
            oacc[mt] = {hb.x, hb.y, hb.z, hb.w};
        }
        #pragma unroll
        for (int kb = 0; kb < 2; kb++) {
            f16x8 bf = *reinterpret_cast<const f16x8*>(&afrag[nt*1024 + kb*512 + 8*l]);
            #pragma unroll
            for (int mt = 0; mt < 4; mt++) {
                f16x8 a = *reinterpret_cast<const f16x8*>(&whp[mt*1024 + kb*512 + 8*l]);
                oacc[mt] = __builtin_amdgcn_mfma_f32_16x16x32_f16(a, bf, oacc[mt], 0, 0, 0);
            }
        }
        int px = nt*16 + (l & 15);
        int yy = wy*8 + (px >> 3), xx = wx*8 + (px & 7);
        size_t pbase = ((size_t)b * HW + (size_t)yy * 512 + xx) * 64;
        #pragma unroll
        for (int mt = 0; mt < 4; mt++) {
            int o0 = mt*16 + (l >> 4)*4;
            uint64_t gg = *reinterpret_cast<const uint64_t*>(
                &gfrag[(px>>4)*1024 + (o0>>3)*128 + (px&15)*8 + (o0&7)]);
            f16x2 g01 = u2h2((uint32_t)gg);
            f16x2 g23 = u2h2((uint32_t)(gg >> 32));
            uint32_t lo = pkrtz_u32(oacc[mt][0] + (float)g01[0],
                                    oacc[mt][1] + (float)g01[1]);
            uint32_t hi = pkrtz_u32(oacc[mt][2] + (float)g23[0],
                                    oacc[mt][3] + (float)g23[1]);
            *reinterpret_cast<uint64_t*>(&s1out[pbase + o0]) =
                (uint64_t)lo | ((uint64_t)hi << 32);
        }
    }
}

// Fused MLP: fc1 (f16 MFMA) + GELU + dwconv3 (pk f16) + fc2 (f16 MFMA) + residual.
// 16x8 tile, halo 18x10; 32 hidden ch/pass; s1 is f16 NHWC; XCD-swizzled grid.
// R12 configuration: LDS-staged sfrag (kept across cc loop), VGPR 64, 4 blocks/CU.
__global__ __launch_bounds__(256, 4) void k3_mlp(
    const uint16_t* __restrict__ s1b, const float* __restrict__ wsw,
    float* __restrict__ out)
{
    __shared__ __align__(16) uint16_t sfrag[12288];  // 24 KB  [12 pt][1024]
    __shared__ __align__(16) uint16_t hbuf[6480];    // 12.96 KB f16 [180 px][36-pad ch]

    const float* f1b = wsw + WS_F1B;
    const float* f2b = wsw + WS_F2B;
    const uint16_t* dwph = (const uint16_t*)(wsw + WS_DWP);
    const uint16_t* w1f  = (const uint16_t*)(wsw + WS_W1F);
    const uint16_t* w2f  = (const uint16_t*)(wsw + WS_W2F);

    int tid = threadIdx.x;
    int wave = tid >> 6, l = tid & 63;
    int hxl = l & 15, cg = l >> 4;
    // bijective XCD swizzle over the 2048 tiles of one batch image (2048 % 8 == 0)
    int flat = blockIdx.y * 32 + blockIdx.x;
    int swz = (flat & 7) * 256 + (flat >> 3);
    int X0 = (swz & 31) * 16, Y0 = (swz >> 5) * 8;
    int b = blockIdx.z;
    bool interior = (X0 > 0) & (X0 < 496) & (Y0 > 0) & (Y0 < 504);

    // ---- phase 0: s1 halo (NHWC f16) -> fragments ----
    if (interior) {
        for (int i = tid; i < 1440; i += 256) {
            int px = i >> 3, g = i & 7;
            int hy = px / 18, hx = px - hy*18;
            int yy = Y0 - 1 + hy, xx = X0 - 1 + hx;
            uint4 q = *reinterpret_cast<const uint4*>(
                &s1b[((size_t)b*HW + (size_t)yy*512 + xx)*64 + g*8]);
            *reinterpret_cast<uint4*>(&sfrag[(px>>4)*1024 + g*128 + (px&15)*8]) = q;
        }
    } else {
        for (int i = tid; i < 1440; i += 256) {
            int px = i >> 3, g = i & 7;
            int hy = px / 18, hx = px - hy*18;
            int yy = Y0 - 1 + hy, xx = X0 - 1 + hx;
            uint4 q = {0u, 0u, 0u, 0u};
            if ((unsigned)yy < 512u && (unsigned)xx < 512u)
                q = *reinterpret_cast<const uint4*>(
                    &s1b[((size_t)b*HW + (size_t)yy*512 + xx)*64 + g*8]);
            *reinterpret_cast<uint4*>(&sfrag[(px>>4)*1024 + g*128 + (px&15)*8]) = q;
        }
    }

    // hoisted fc1-store invariants (3 pt iterations, invariant across cc)
    bool okA[3], imgA[3];
    int hbA[3], ptA[3];
    #pragma unroll
    for (int it = 0; it < 3; it++) {
        int pt = wave + it*4;
        int px = pt*16 + hxl;
        ptA[it] = pt;
        okA[it] = px < 180;
        int hy = px / 18, hx = px - hy*18;
        imgA[it] = okA[it] &&
            (interior || (((unsigned)(Y0-1+hy) < 512u) && ((unsigned)(X0-1+hx) < 512u)));
        hbA[it] = px*36 + cg*4;
    }

    f32x4 acc[2][4];
    #pragma unroll
    for (int nt = 0; nt < 4; nt++) {
        float bias = f2b[nt*16 + (l & 15)];
        acc[0][nt] = {bias, bias, bias, bias};
        acc[1][nt] = acc[0][nt];
    }
    __syncthreads();

    for (int cc = 0; cc < 8; cc++) {
        // ---- fc1 (A = weights, B = pixels) + GELU -> hbuf (f16) ----
        f16x8 wA[2][2];
        #pragma unroll
        for (int mtw = 0; mtw < 2; mtw++)
            #pragma unroll
            for (int kb = 0; kb < 2; kb++)
                wA[mtw][kb] = *reinterpret_cast<const f16x8*>(
                    &w1f[(cc*2 + mtw)*1024 + kb*512 + 8*l]);
        float4 hb0 = *reinterpret_cast<const float4*>(&f1b[cc*32      + cg*4]);
        float4 hb1 = *reinterpret_cast<const float4*>(&f1b[cc*32 + 16 + cg*4]);

        #pragma unroll
        for (int it = 0; it < 3; it++) {
            int pt = ptA[it];
            f32x4 h0 = {hb0.x, hb0.y, hb0.z, hb0.w};
            f32x4 h1 = {hb1.x, hb1.y, hb1.z, hb1.w};
            #pragma unroll
            for (int kb = 0; kb < 2; kb++) {
                f16x8 bf = *reinterpret_cast<const f16x8*>(&sfrag[pt*1024 + kb*512 + 8*l]);
                h0 = __builtin_amdgcn_mfma_f32_16x16x32_f16(wA[0][kb], bf, h0, 0, 0, 0);
                h1 = __builtin_amdgcn_mfma_f32_16x16x32_f16(wA[1][kb], bf, h1, 0, 0, 0);
            }
            if (okA[it]) {
                uint64_t v0 = 0, v1 = 0;
                if (imgA[it]) {
                    uint32_t a01 = pkrtz_u32(gelu_f(h0[0]), gelu_f(h0[1]));
                    uint32_t a23 = pkrtz_u32(gelu_f(h0[2]), gelu_f(h0[3]));
                    uint32_t b01 = pkrtz_u32(gelu_f(h1[0]), gelu_f(h1[1]));
                    uint32_t b23 = pkrtz_u32(gelu_f(h1[2]), gelu_f(h1[3]));
                    v0 = (uint64_t)a01 | ((uint64_t)a23 << 32);
                    v1 = (uint64_t)b01 | ((uint64_t)b23 << 32);
                }
                *reinterpret_cast<uint64_t*>(&hbuf[hbA[it]])      = v0;
                *reinterpret_cast<uint64_t*>(&hbuf[hbA[it] + 16]) = v1;
            }
        }
        __syncthreads();

        // ---- dwconv (f16 pk math, 8 ch/thread) + fc2 f16 MFMA ----
        f16x8 bfr[4];
        #pragma unroll
        for (int nt = 0; nt < 4; nt++)
            bfr[nt] = *reinterpret_cast<const f16x8*>(&w2f[nt*4096 + cc*512 + 8*l]);

        uint4 R[4][3];
        #pragma unroll
        for (int tr = 0; tr < 4; tr++)
            #pragma unroll
            for (int dx = 0; dx < 3; dx++)
                R[tr][dx] = *reinterpret_cast<const uint4*>(
                    &hbuf[((wave*2 + tr)*18 + hxl + dx)*36 + cg*8]);

        union { f16x2 h[4]; f16x8 v; } t0, t1;
        f16x2 z = {(_Float16)0.f, (_Float16)0.f};
        #pragma unroll
        for (int g = 0; g < 4; g++) { t0.h[g] = z; t1.h[g] = z; }

        #pragma unroll
        for (int dy = 0; dy < 3; dy++) {
            #pragma unroll
            for (int dx = 0; dx < 3; dx++) {
                uint4 w = *reinterpret_cast<const uint4*>(
                    &dwph[(dy*3+dx)*256 + cc*32 + cg*8]);
                uint4 qa = R[dy][dx];
                uint4 qb = R[dy+1][dx];
                t0.h[0] += u2h2(qa.x) * u2h2(w.x);
                t0.h[1] += u2h2(qa.y) * u2h2(w.y);
                t0.h[2] += u2h2(qa.z) * u2h2(w.z);
                t0.h[3] += u2h2(qa.w) * u2h2(w.w);
                t1.h[0] += u2h2(qb.x) * u2h2(w.x);
                t1.h[1] += u2h2(qb.y) * u2h2(w.y);
                t1.h[2] += u2h2(qb.z) * u2h2(w.z);
                t1.h[3] += u2h2(qb.w) * u2h2(w.w);
            }
        }
        #pragma unroll
        for (int nt = 0; nt < 4; nt++) {
            acc[0][nt] = __builtin_amdgcn_mfma_f32_16x16x32_f16(t0.v, bfr[nt], acc[0][nt], 0, 0, 0);
            acc[1][nt] = __builtin_amdgcn_mfma_f32_16x16x32_f16(t1.v, bfr[nt], acc[1][nt], 0, 0, 0);
        }
        __syncthreads();
    }

    // ---- epilogue: + residual (f16 NHWC s1) -> out (f32 NCHW) ----
    int r0 = cg * 4;
    #pragma unroll
    for (int mi = 0; mi < 2; mi++) {
        int yrow = Y0 + wave*2 + mi;
        size_t srow = ((size_t)b*HW + (size_t)yrow*512 + X0 + r0) * 64;
        #pragma unroll
        for (int nt = 0; nt < 4; nt++) {
            int o = nt*16 + (l & 15);
            size_t oidx = ((size_t)b*CH + o)*HW + (size_t)yrow*512 + X0 + r0;
            float4 ov;
            ov.x = acc[mi][nt][0] + h2f(s1b[srow + o]);
            ov.y = acc[mi][nt][1] + h2f(s1b[srow + 64 + o]);
            ov.z = acc[mi][nt][2] + h2f(s1b[srow + 128 + o]);
            ov.w = acc[mi][nt][3] + h2f(s1b[srow + 192 + o]);
            *reinterpret_cast<float4*>(out + oidx) = ov;
        }
    }
}

extern "C" void kernel_launch(void* const* d_in, const int* in_sizes, int n_in,
                              void* d_out, int out_size, void* d_ws, size_t ws_size,
                              hipStream_t stream) {
    const float* x     = (const float*)d_in[0];
    const float* pa_w  = (const float*)d_in[1];
    const float* pa_b  = (const float*)d_in[2];
    const float* bn1_g = (const float*)d_in[3];
    const float* bn1_b = (const float*)d_in[4];
    const float* bn1_m = (const float*)d_in[5];
    const float* bn1_v = (const float*)d_in[6];
    const float* q_w   = (const float*)d_in[7];
    const float* q_b   = (const float*)d_in[8];
    const float* k_w   = (const float*)d_in[9];
    const float* k_b   = (const float*)d_in[10];
    const float* v_w   = (const float*)d_in[11];
    const float* v_b   = (const float*)d_in[12];
    const float* hp_w  = (const float*)d_in[13];
    const float* hp_b  = (const float*)d_in[14];
    const float* bn2_g = (const float*)d_in[15];
    const float* bn2_b = (const float*)d_in[16];
    const float* bn2_m = (const float*)d_in[17];
    const float* bn2_v = (const float*)d_in[18];
    const float* fc1_w = (const float*)d_in[19];
    const float* fc1_b = (const float*)d_in[20];
    const float* dw_w  = (const float*)d_in[21];
    const float* dw_b  = (const float*)d_in[22];
    const float* bn3_g = (const float*)d_in[23];
    const float* bn3_b = (const float*)d_in[24];
    const float* bn3_m = (const float*)d_in[25];
    const float* bn3_v = (const float*)d_in[26];
    const float* fc2_w = (const float*)d_in[27];
    const float* fc2_b = (const float*)d_in[28];

    uint16_t* s1b = (uint16_t*)d_ws;                                 // 67,108,864 B
    float*    wsw = (float*)((char*)d_ws + 134217728 + 268435456);   // ~100 KB

    k0_fold<<<dim3(1), dim3(256), 0, stream>>>(
        q_w, q_b, k_w, k_b, v_w, v_b,
        bn1_g, bn1_b, bn1_m, bn1_v,
        fc1_w, fc1_b, bn2_g, bn2_b, bn2_m, bn2_v,
        fc2_w, fc2_b, hp_w, dw_w, dw_b, bn3_g, bn3_b, bn3_m, bn3_v, wsw);

    k2_attn<<<dim3(8192), dim3(256), 0, stream>>>(
        x, pa_w, pa_b, hp_b, wsw, s1b);

    k3_mlp<<<dim3(32, 64, 2), dim3(256), 0, stream>>>(
        s1b, wsw, (float*)d_out);
}